// Round 2
// baseline (576.383 us; speedup 1.0000x reference)
//
#include <hip/hip_runtime.h>

#define A_DIM 6
#define HID_D 64
#define LATENT_D 64
#define GRU_IN_D 134
#define T_STEPS 128
#define N_ENV 10
#define BN_TOT 640
#define NB 2                      // rollouts per block (interleaved in wave 0)

typedef float f2 __attribute__((ext_vector_type(2)));

__device__ __forceinline__ float fast_sigmoid(float x) {
    return __builtin_amdgcn_rcpf(1.0f + __builtin_amdgcn_exp2f(-1.4426950408889634f * x));
}
__device__ __forceinline__ float fast_tanh(float x) {
    return 1.0f - 2.0f * __builtin_amdgcn_rcpf(1.0f + __builtin_amdgcn_exp2f(2.8853900817779268f * x));
}

template<int CTRL>
__device__ __forceinline__ float dppadd(float v) {
    int t = __builtin_amdgcn_update_dpp(0, __builtin_bit_cast(int, v), CTRL, 0xf, 0xf, true);
    return v + __builtin_bit_cast(float, t);
}
// sum over all 64 lanes -> wave-uniform scalar (VALU pipe only)
__device__ __forceinline__ float wave_reduce_add(float v) {
    v = dppadd<0x111>(v);   // row_shr:1
    v = dppadd<0x112>(v);   // row_shr:2
    v = dppadd<0x114>(v);   // row_shr:4
    v = dppadd<0x118>(v);   // row_shr:8
    v = dppadd<0x142>(v);   // row_bcast:15
    v = dppadd<0x143>(v);   // row_bcast:31 -> lane 63 has total
    return __builtin_bit_cast(float, __builtin_amdgcn_readlane(__builtin_bit_cast(int, v), 63));
}

__global__ __launch_bounds__(256, 2)
void policy_kernel(const float* __restrict__ s_h,
                   const int*   __restrict__ a_h,
                   const float* __restrict__ b_z,
                   const float* __restrict__ conv1_w, const float* __restrict__ conv1_b,
                   const float* __restrict__ conv2_w, const float* __restrict__ conv2_b,
                   const float* __restrict__ fc_w,    const float* __restrict__ fc_b,
                   const float* __restrict__ emb,
                   const float* __restrict__ gru_wih, const float* __restrict__ gru_whh,
                   const float* __restrict__ gru_bih, const float* __restrict__ gru_bhh,
                   const float* __restrict__ mlp1_w,  const float* __restrict__ mlp1_b,
                   const float* __restrict__ mlp2_w,  const float* __restrict__ mlp2_b,
                   float* __restrict__ logits_out, float* __restrict__ mask_out)
{
    __shared__ __align__(16) float s0[NB][512];      // frame0 per bn
    __shared__ __align__(16) float a1[NB][1152];     // conv1 out per bn
    __shared__ __align__(16) float a2[NB][512];      // conv2 out per bn
    __shared__ __align__(16) float pfc[NB][128];     // fc partials per bn
    __shared__ __align__(16) float semb[NB][64];
    __shared__ __align__(16) float gxc[NB][192];     // step-invariant gx per bn
    __shared__ __align__(16) float hspec[NB][6*64];  // speculative h per action per bn
    // Transposed-paired weights (bn-independent, conflict-free b64 reads):
    //   lwn2[k2*64 + j] = { Whh_n[j][2k2], Whh_n[j][2k2+1] }
    //   lw12[k2*64 + j] = { mlp1_w[j][2k2], mlp1_w[j][2k2+1] }
    __shared__ f2 lwn2[2048];
    __shared__ f2 lw12[2048];

    const int bn0  = blockIdx.x * NB;
    const int tid  = threadIdx.x;        // 0..255
    const int b    = tid >> 7;           // which bn this thread preambles
    const int ltid = tid & 127;
    const int j    = tid & 63;
    const int w    = (tid >> 6) & 1;     // wave within the bn pair
    const int bn   = bn0 + b;

    // ---- masks output (256 threads cover 2 x 128) ----
    mask_out[bn * T_STEPS + ltid] = (a_h[bn * T_STEPS + ltid] != (A_DIM - 1)) ? 1.0f : 0.0f;

    // ---- load frame 0 for own bn ----
    {
        const float* src = s_h + (size_t)bn * T_STEPS * 512;
        #pragma unroll
        for (int i = 0; i < 4; ++i) s0[b][ltid + i * 128] = src[ltid + i * 128];
    }

    // ---- stage wn / w1 into LDS (transposed f2 pairs), all 256 threads ----
    for (int i2 = tid; i2 < 2048; i2 += 256) {
        const int k2 = i2 >> 6, jj = i2 & 63;
        lwn2[i2] = *(const f2*)&gru_whh[(128 + jj) * 64 + 2 * k2];
        lw12[i2] = *(const f2*)&mlp1_w[(size_t)jj * 64 + 2 * k2];
    }
    __syncthreads();

    // ---- conv1: (8,8,8) -> (32,6,6), ReLU ----
    for (int i = ltid; i < 1152; i += 128) {
        const int oc = i / 36, r = i % 36, oh = r / 6, ow = r % 6;
        float sum = conv1_b[oc];
        const float* wp = conv1_w + oc * 72;
        #pragma unroll
        for (int ic = 0; ic < 8; ++ic)
            #pragma unroll
            for (int kh = 0; kh < 3; ++kh)
                #pragma unroll
                for (int kw = 0; kw < 3; ++kw)
                    sum = fmaf(s0[b][ic * 64 + (oh + kh) * 8 + (ow + kw)],
                               wp[ic * 9 + kh * 3 + kw], sum);
        a1[b][i] = fmaxf(sum, 0.0f);
    }
    __syncthreads();

    // ---- conv2: (32,6,6) -> (32,4,4), ReLU ----
    for (int i = ltid; i < 512; i += 128) {
        const int oc = i / 16, r = i % 16, oh = r / 4, ow = r % 4;
        float sum = conv2_b[oc];
        const float* wp = conv2_w + oc * 288;
        for (int ic = 0; ic < 32; ++ic)
            #pragma unroll
            for (int kh = 0; kh < 3; ++kh)
                #pragma unroll
                for (int kw = 0; kw < 3; ++kw)
                    sum = fmaf(a1[b][ic * 36 + (oh + kh) * 6 + (ow + kw)],
                               wp[ic * 9 + kh * 3 + kw], sum);
        a2[b][i] = fmaxf(sum, 0.0f);
    }
    __syncthreads();

    // ---- fc: 512 -> 64, ReLU (k-split across the bn's 2 waves) ----
    {
        const float* wp = fc_w + j * 512 + w * 256;
        const float* ap = a2[b] + w * 256;
        float s0a = 0.f, s1a = 0.f, s2a = 0.f, s3a = 0.f;
        for (int k = 0; k < 256; k += 4) {
            s0a = fmaf(ap[k + 0], wp[k + 0], s0a);
            s1a = fmaf(ap[k + 1], wp[k + 1], s1a);
            s2a = fmaf(ap[k + 2], wp[k + 2], s2a);
            s3a = fmaf(ap[k + 3], wp[k + 3], s3a);
        }
        pfc[b][ltid] = (s0a + s1a) + (s2a + s3a);
    }
    __syncthreads();
    if (ltid < 64) semb[b][ltid] = fmaxf(pfc[b][ltid] + pfc[b][ltid + 64] + fc_b[ltid], 0.0f);
    __syncthreads();

    // ---- step-invariant gx for own bn ----
    {
        const float* bz = b_z + (size_t)(bn / N_ENV) * LATENT_D;
        for (int g = ltid; g < 192; g += 128) {
            float sum = gru_bih[g] + ((g < 128) ? gru_bhh[g] : 0.0f);
            const float* wp = gru_wih + g * GRU_IN_D;
            for (int k = 0; k < 64; ++k) sum = fmaf(semb[b][k], wp[k], sum);
            for (int k = 0; k < 64; ++k) sum = fmaf(bz[k], wp[70 + k], sum);
            gxc[b][g] = sum;
        }
    }
    __syncthreads();

    if (tid >= 64) return;   // rollout: single wave interleaving both bn

    // ---- per-lane fp32 weights wr/wz (bn-independent, 128 VGPRs) ----
    f2 wr[32], wz[32];
    {
        const float* pr = gru_whh + (size_t)j * 64;
        const float* pz = gru_whh + (size_t)(64 + j) * 64;
        #pragma unroll
        for (int i = 0; i < 16; ++i) {
            float4 v;
            v = ((const float4*)pr)[i]; wr[2*i] = (f2){v.x, v.y}; wr[2*i+1] = (f2){v.z, v.w};
            v = ((const float4*)pz)[i]; wz[2*i] = (f2){v.x, v.y}; wz[2*i+1] = (f2){v.z, v.w};
        }
    }
    const float bhn = gru_bhh[128 + j];
    const float b1j = mlp1_b[j];
    float m2c[6], b2v[6];
    #pragma unroll
    for (int a = 0; a < 6; ++a) { m2c[a] = mlp2_w[a * 64 + j]; b2v[a] = mlp2_b[a]; }

    // bn-independent action-embedding contribution (was atab): per-lane regs
    float arx0[6], azx0[6], anx0[6], arx1[6], azx1[6], anx1[6];
    {
        float wqr[6], wqz[6], wqn[6];
        #pragma unroll
        for (int q = 0; q < 6; ++q) {
            wqr[q] = gru_wih[j * GRU_IN_D + 64 + q];
            wqz[q] = gru_wih[(64 + j) * GRU_IN_D + 64 + q];
            wqn[q] = gru_wih[(128 + j) * GRU_IN_D + 64 + q];
        }
        const float g0r = gxc[0][j], g0z = gxc[0][64 + j], g0n = gxc[0][128 + j];
        const float g1r = gxc[1][j], g1z = gxc[1][64 + j], g1n = gxc[1][128 + j];
        #pragma unroll
        for (int a = 0; a < 6; ++a) {
            float sr = 0.f, sz = 0.f, sn = 0.f;
            #pragma unroll
            for (int q = 0; q < 6; ++q) {
                const float e = emb[a * 6 + q];
                sr = fmaf(e, wqr[q], sr);
                sz = fmaf(e, wqz[q], sz);
                sn = fmaf(e, wqn[q], sn);
            }
            arx0[a] = g0r + sr; azx0[a] = g0z + sz; anx0[a] = g0n + sn;
            arx1[a] = g1r + sr; azx1[a] = g1z + sz; anx1[a] = g1n + sn;
        }
    }

    // per-lane LDS bases for transposed weight reads (lane j's column)
    const f2* __restrict__ wnj = lwn2 + j;   // index k2*64
    const f2* __restrict__ w1j = lw12 + j;

    // ---- seed: speculative h_1 candidates from h_0 = 0 (hr=hz=0, hn=bhn) ----
    float ha0[6], ha1[6];
    #pragma unroll
    for (int a = 0; a < 6; ++a) {
        float r = fast_sigmoid(arx0[a]);
        float z = fast_sigmoid(azx0[a]);
        float n = fast_tanh(fmaf(r, bhn, anx0[a]));
        ha0[a] = fmaf(z, 0.0f - n, n);
        r = fast_sigmoid(arx1[a]);
        z = fast_sigmoid(azx1[a]);
        n = fast_tanh(fmaf(r, bhn, anx1[a]));
        ha1[a] = fmaf(z, 0.0f - n, n);
    }
    __builtin_amdgcn_wave_barrier();
    #pragma unroll
    for (int a = 0; a < 6; ++a) {
        hspec[0][a * 64 + j] = ha0[a];
        hspec[1][a * 64 + j] = ha1[a];
    }
    __builtin_amdgcn_wave_barrier();

    int act0 = A_DIM - 1, act1 = A_DIM - 1;
    float* lo0 = logits_out + (size_t)(bn0 + 0) * (T_STEPS - 1) * A_DIM;
    float* lo1 = logits_out + (size_t)(bn0 + 1) * (T_STEPS - 1) * A_DIM;

    for (int t = 0; t < T_STEPS - 1; ++t) {
        const float4* hbA = (const float4*)(hspec[0] + (act0 << 6));
        const float4* hbB = (const float4*)(hspec[1] + (act1 << 6));
        float hp0 = ha0[0], hp1 = ha1[0];
        #pragma unroll
        for (int a = 1; a < 6; ++a) {
            hp0 = (act0 == a) ? ha0[a] : hp0;
            hp1 = (act1 == a) ? ha1[a] : hp1;
        }

        // fused sweep for BOTH rollouts; weight f2s loaded once, used twice
        f2 pr0 = {0.f,0.f}, pz0 = {0.f,0.f}, pn0 = {0.f,0.f}, p10 = {0.f,0.f};
        f2 pr1 = {0.f,0.f}, pz1 = {0.f,0.f}, pn1 = {0.f,0.f}, p11 = {0.f,0.f};
        #pragma unroll
        for (int i = 0; i < 16; ++i) {
            const float4 hv0 = hbA[i];
            const float4 hv1 = hbB[i];
            const f2 h0A = (f2){hv0.x, hv0.y}, h0B = (f2){hv0.z, hv0.w};
            const f2 h1A = (f2){hv1.x, hv1.y}, h1B = (f2){hv1.z, hv1.w};
            const f2 wnA = wnj[(2*i) * 64], wnB = wnj[(2*i+1) * 64];
            const f2 w1A = w1j[(2*i) * 64], w1B = w1j[(2*i+1) * 64];
            pr0 += h0A * wr[2*i]; pr0 += h0B * wr[2*i+1];
            pr1 += h1A * wr[2*i]; pr1 += h1B * wr[2*i+1];
            pz0 += h0A * wz[2*i]; pz0 += h0B * wz[2*i+1];
            pz1 += h1A * wz[2*i]; pz1 += h1B * wz[2*i+1];
            pn0 += h0A * wnA;     pn0 += h0B * wnB;
            pn1 += h1A * wnA;     pn1 += h1B * wnB;
            p10 += h0A * w1A;     p10 += h0B * w1B;
            p11 += h1A * w1A;     p11 += h1B * w1B;
        }
        const float hid0 = fast_tanh(p10.x + p10.y + b1j);
        const float hid1 = fast_tanh(p11.x + p11.y + b1j);
        const float hr0 = pr0.x + pr0.y, hz0 = pz0.x + pz0.y, hn0 = pn0.x + pn0.y + bhn;
        const float hr1 = pr1.x + pr1.y, hz1 = pz1.x + pz1.y, hn1 = pn1.x + pn1.y + bhn;

        // mlp2 via DPP wave reductions (12 independent chains interleave)
        const float l00 = wave_reduce_add(hid0 * m2c[0]) + b2v[0];
        const float l01 = wave_reduce_add(hid0 * m2c[1]) + b2v[1];
        const float l02 = wave_reduce_add(hid0 * m2c[2]) + b2v[2];
        const float l03 = wave_reduce_add(hid0 * m2c[3]) + b2v[3];
        const float l04 = wave_reduce_add(hid0 * m2c[4]) + b2v[4];
        const float l05 = wave_reduce_add(hid0 * m2c[5]) + b2v[5];
        const float l10 = wave_reduce_add(hid1 * m2c[0]) + b2v[0];
        const float l11 = wave_reduce_add(hid1 * m2c[1]) + b2v[1];
        const float l12 = wave_reduce_add(hid1 * m2c[2]) + b2v[2];
        const float l13 = wave_reduce_add(hid1 * m2c[3]) + b2v[3];
        const float l14 = wave_reduce_add(hid1 * m2c[4]) + b2v[4];
        const float l15 = wave_reduce_add(hid1 * m2c[5]) + b2v[5];

        // speculative gates for ALL 6 actions, both rollouts (fills DPP window)
        #pragma unroll
        for (int a = 0; a < 6; ++a) {
            float r = fast_sigmoid(arx0[a] + hr0);
            float z = fast_sigmoid(azx0[a] + hz0);
            float n = fast_tanh(fmaf(r, hn0, anx0[a]));
            ha0[a] = fmaf(z, hp0 - n, n);
            r = fast_sigmoid(arx1[a] + hr1);
            z = fast_sigmoid(azx1[a] + hz1);
            n = fast_tanh(fmaf(r, hn1, anx1[a]));
            ha1[a] = fmaf(z, hp1 - n, n);
        }
        __builtin_amdgcn_wave_barrier();
        #pragma unroll
        for (int a = 0; a < 6; ++a) {
            hspec[0][a * 64 + j] = ha0[a];
            hspec[1][a * 64 + j] = ha1[a];
        }
        __builtin_amdgcn_wave_barrier();

        // argmax, first-max-wins
        float best0 = l00; int bi0 = 0;
        if (l01 > best0) { best0 = l01; bi0 = 1; }
        if (l02 > best0) { best0 = l02; bi0 = 2; }
        if (l03 > best0) { best0 = l03; bi0 = 3; }
        if (l04 > best0) { best0 = l04; bi0 = 4; }
        if (l05 > best0) { best0 = l05; bi0 = 5; }
        act0 = bi0;
        float best1 = l10; int bi1 = 0;
        if (l11 > best1) { best1 = l11; bi1 = 1; }
        if (l12 > best1) { best1 = l12; bi1 = 2; }
        if (l13 > best1) { best1 = l13; bi1 = 3; }
        if (l14 > best1) { best1 = l14; bi1 = 4; }
        if (l15 > best1) { best1 = l15; bi1 = 5; }
        act1 = bi1;

        if (j < A_DIM) {
            const float o0 = (j == 0) ? l00 : (j == 1) ? l01 : (j == 2) ? l02
                           : (j == 3) ? l03 : (j == 4) ? l04 : l05;
            const float o1 = (j == 0) ? l10 : (j == 1) ? l11 : (j == 2) ? l12
                           : (j == 3) ? l13 : (j == 4) ? l14 : l15;
            lo0[t * A_DIM + j] = o0;
            lo1[t * A_DIM + j] = o1;
        }
    }
}

extern "C" void kernel_launch(void* const* d_in, const int* in_sizes, int n_in,
                              void* d_out, int out_size, void* d_ws, size_t ws_size,
                              hipStream_t stream) {
    const float* s_h     = (const float*)d_in[0];
    const int*   a_h     = (const int*)  d_in[1];
    const float* b_z     = (const float*)d_in[2];
    const float* conv1_w = (const float*)d_in[3];
    const float* conv1_b = (const float*)d_in[4];
    const float* conv2_w = (const float*)d_in[5];
    const float* conv2_b = (const float*)d_in[6];
    const float* fc_w    = (const float*)d_in[7];
    const float* fc_b    = (const float*)d_in[8];
    const float* emb     = (const float*)d_in[9];
    const float* gru_wih = (const float*)d_in[10];
    const float* gru_whh = (const float*)d_in[11];
    const float* gru_bih = (const float*)d_in[12];
    const float* gru_bhh = (const float*)d_in[13];
    const float* mlp1_w  = (const float*)d_in[14];
    const float* mlp1_b  = (const float*)d_in[15];
    const float* mlp2_w  = (const float*)d_in[16];
    const float* mlp2_b  = (const float*)d_in[17];

    float* out = (float*)d_out;
    float* logits_out = out;                                          // (B,N,127,6)
    float* mask_out   = out + (size_t)BN_TOT * (T_STEPS - 1) * A_DIM; // (B,N,128,1)

    policy_kernel<<<BN_TOT / NB, 256, 0, stream>>>(
        s_h, a_h, b_z, conv1_w, conv1_b, conv2_w, conv2_b, fc_w, fc_b, emb,
        gru_wih, gru_whh, gru_bih, gru_bhh, mlp1_w, mlp1_b, mlp2_w, mlp2_b,
        logits_out, mask_out);
}

// Round 3
// 502.602 us; speedup vs baseline: 1.1468x; 1.1468x over previous
//
#include <hip/hip_runtime.h>

#define A_DIM 6
#define HID_D 64
#define LATENT_D 64
#define GRU_IN_D 134
#define T_STEPS 128
#define N_ENV 10
#define BN_TOT 640

typedef float f2 __attribute__((ext_vector_type(2)));

__device__ __forceinline__ float fast_sigmoid(float x) {
    return __builtin_amdgcn_rcpf(1.0f + __builtin_amdgcn_exp2f(-1.4426950408889634f * x));
}
__device__ __forceinline__ float fast_tanh(float x) {
    return 1.0f - 2.0f * __builtin_amdgcn_rcpf(1.0f + __builtin_amdgcn_exp2f(2.8853900817779268f * x));
}

template<int CTRL>
__device__ __forceinline__ float dppadd(float v) {
    int t = __builtin_amdgcn_update_dpp(0, __builtin_bit_cast(int, v), CTRL, 0xf, 0xf, true);
    return v + __builtin_bit_cast(float, t);
}
// sum over all 64 lanes -> wave-uniform scalar (VALU pipe only)
__device__ __forceinline__ float wave_reduce_add(float v) {
    v = dppadd<0x111>(v);   // row_shr:1
    v = dppadd<0x112>(v);   // row_shr:2
    v = dppadd<0x114>(v);   // row_shr:4
    v = dppadd<0x118>(v);   // row_shr:8
    v = dppadd<0x142>(v);   // row_bcast:15
    v = dppadd<0x143>(v);   // row_bcast:31 -> lane 63 has total
    return __builtin_bit_cast(float, __builtin_amdgcn_readlane(__builtin_bit_cast(int, v), 63));
}

// Single wave per block; pin 1 wave/EU so the backend budget is the full
// 512-VGPR file (R0/R1 showed the heuristic capping at ~160 and spilling
// the 256 VGPRs of weights into AGPRs/LDS).
__global__ __launch_bounds__(64) __attribute__((amdgpu_waves_per_eu(1, 1)))
void policy_kernel(const float* __restrict__ s_h,
                   const int*   __restrict__ a_h,
                   const float* __restrict__ b_z,
                   const float* __restrict__ conv1_w, const float* __restrict__ conv1_b,
                   const float* __restrict__ conv2_w, const float* __restrict__ conv2_b,
                   const float* __restrict__ fc_w,    const float* __restrict__ fc_b,
                   const float* __restrict__ emb,
                   const float* __restrict__ gru_wih, const float* __restrict__ gru_whh,
                   const float* __restrict__ gru_bih, const float* __restrict__ gru_bhh,
                   const float* __restrict__ mlp1_w,  const float* __restrict__ mlp1_b,
                   const float* __restrict__ mlp2_w,  const float* __restrict__ mlp2_b,
                   float* __restrict__ logits_out, float* __restrict__ mask_out)
{
    __shared__ __align__(16) float s0[512];      // frame0 [c][h][w]
    __shared__ __align__(16) float a1[1152];     // conv1 out [32][36]
    __shared__ __align__(16) float a2[512];      // conv2 out flat
    __shared__ __align__(16) float semb[64];
    __shared__ __align__(16) float gxc[192];     // step-invariant gx (+biases)
    __shared__ __align__(16) float hspec[6*64];  // speculative h_{t+1} per action

    const int bn  = blockIdx.x;          // 0..639
    const int tid = threadIdx.x;         // 0..63 — one wave does everything
    const int j   = tid;

    // ---- masks output ----
    #pragma unroll
    for (int i = 0; i < 2; ++i) {
        const int t = tid + i * 64;
        mask_out[bn * T_STEPS + t] = (a_h[bn * T_STEPS + t] != (A_DIM - 1)) ? 1.0f : 0.0f;
    }

    // ---- load frame 0 ----
    {
        const float* src = s_h + (size_t)bn * T_STEPS * 512;
        #pragma unroll
        for (int i = 0; i < 8; ++i) s0[tid + i * 64] = src[tid + i * 64];
    }
    __syncthreads();

    // ---- conv1: (8,8,8) -> (32,6,6), ReLU ----
    for (int i = tid; i < 1152; i += 64) {
        const int oc = i / 36, r = i % 36, oh = r / 6, ow = r % 6;
        float sum = conv1_b[oc];
        const float* wp = conv1_w + oc * 72;
        #pragma unroll
        for (int ic = 0; ic < 8; ++ic)
            #pragma unroll
            for (int kh = 0; kh < 3; ++kh)
                #pragma unroll
                for (int kw = 0; kw < 3; ++kw)
                    sum = fmaf(s0[ic * 64 + (oh + kh) * 8 + (ow + kw)],
                               wp[ic * 9 + kh * 3 + kw], sum);
        a1[i] = fmaxf(sum, 0.0f);
    }
    __syncthreads();

    // ---- conv2: (32,6,6) -> (32,4,4), ReLU ----
    for (int i = tid; i < 512; i += 64) {
        const int oc = i / 16, r = i % 16, oh = r / 4, ow = r % 4;
        float sum = conv2_b[oc];
        const float* wp = conv2_w + oc * 288;
        for (int ic = 0; ic < 32; ++ic)
            #pragma unroll
            for (int kh = 0; kh < 3; ++kh)
                #pragma unroll
                for (int kw = 0; kw < 3; ++kw)
                    sum = fmaf(a1[ic * 36 + (oh + kh) * 6 + (ow + kw)],
                               wp[ic * 9 + kh * 3 + kw], sum);
        a2[i] = fmaxf(sum, 0.0f);
    }
    __syncthreads();

    // ---- fc: 512 -> 64, ReLU (full dot per lane) ----
    {
        const float* wp = fc_w + j * 512;
        float s0a = 0.f, s1a = 0.f, s2a = 0.f, s3a = 0.f;
        for (int k = 0; k < 512; k += 4) {
            s0a = fmaf(a2[k + 0], wp[k + 0], s0a);
            s1a = fmaf(a2[k + 1], wp[k + 1], s1a);
            s2a = fmaf(a2[k + 2], wp[k + 2], s2a);
            s3a = fmaf(a2[k + 3], wp[k + 3], s3a);
        }
        semb[j] = fmaxf((s0a + s1a) + (s2a + s3a) + fc_b[j], 0.0f);
    }
    __syncthreads();

    // ---- step-invariant gx ----
    {
        const float* bz = b_z + (size_t)(bn / N_ENV) * LATENT_D;
        for (int g = tid; g < 192; g += 64) {
            float sum = gru_bih[g] + ((g < 128) ? gru_bhh[g] : 0.0f);
            const float* wp = gru_wih + g * GRU_IN_D;
            for (int k = 0; k < 64; ++k) sum = fmaf(semb[k], wp[k], sum);
            for (int k = 0; k < 64; ++k) sum = fmaf(bz[k], wp[70 + k], sum);
            gxc[g] = sum;
        }
    }
    __syncthreads();

    // ---- per-lane fp32 weights: ALL FOUR matrices resident (256 VGPRs) ----
    f2 wr[32], wz[32], wn[32], w1[32];
    {
        const float* pr = gru_whh + (size_t)j * 64;
        const float* pz = gru_whh + (size_t)(64 + j) * 64;
        const float* pn = gru_whh + (size_t)(128 + j) * 64;
        const float* p1 = mlp1_w + (size_t)j * 64;
        #pragma unroll
        for (int i = 0; i < 16; ++i) {
            float4 v;
            v = ((const float4*)pr)[i]; wr[2*i] = (f2){v.x, v.y}; wr[2*i+1] = (f2){v.z, v.w};
            v = ((const float4*)pz)[i]; wz[2*i] = (f2){v.x, v.y}; wz[2*i+1] = (f2){v.z, v.w};
            v = ((const float4*)pn)[i]; wn[2*i] = (f2){v.x, v.y}; wn[2*i+1] = (f2){v.z, v.w};
            v = ((const float4*)p1)[i]; w1[2*i] = (f2){v.x, v.y}; w1[2*i+1] = (f2){v.z, v.w};
        }
    }
    const float bhn = gru_bhh[128 + j];
    const float b1j = mlp1_b[j];

    // step-invariant per-action gate inputs (action-embedding term in regs)
    float arx[6], azx[6], anx[6], m2c[6], b2[6];
    {
        float wqr[6], wqz[6], wqn[6];
        #pragma unroll
        for (int q = 0; q < 6; ++q) {
            wqr[q] = gru_wih[j * GRU_IN_D + 64 + q];
            wqz[q] = gru_wih[(64 + j) * GRU_IN_D + 64 + q];
            wqn[q] = gru_wih[(128 + j) * GRU_IN_D + 64 + q];
        }
        const float gxr = gxc[j], gxz = gxc[64 + j], gxn = gxc[128 + j];
        #pragma unroll
        for (int a = 0; a < 6; ++a) {
            float sr = 0.f, sz = 0.f, sn = 0.f;
            #pragma unroll
            for (int q = 0; q < 6; ++q) {
                const float e = emb[a * 6 + q];
                sr = fmaf(e, wqr[q], sr);
                sz = fmaf(e, wqz[q], sz);
                sn = fmaf(e, wqn[q], sn);
            }
            arx[a] = gxr + sr;
            azx[a] = gxz + sz;
            anx[a] = gxn + sn;
            m2c[a] = mlp2_w[a * 64 + j];
            b2[a] = mlp2_b[a];
        }
    }

    // ---- seed: speculative h_1 candidates from h_0 = 0 (hr=hz=0, hn=bhn) ----
    float ha[6];
    #pragma unroll
    for (int a = 0; a < 6; ++a) {
        const float r = fast_sigmoid(arx[a]);
        const float z = fast_sigmoid(azx[a]);
        const float n = fast_tanh(fmaf(r, bhn, anx[a]));
        ha[a] = fmaf(z, 0.0f - n, n);            // (1-z)*n + z*0
    }
    __builtin_amdgcn_wave_barrier();
    #pragma unroll
    for (int a = 0; a < 6; ++a) hspec[a * 64 + j] = ha[a];
    __builtin_amdgcn_wave_barrier();

    int act = A_DIM - 1;
    float* lout = logits_out + (size_t)bn * (T_STEPS - 1) * A_DIM;

    for (int t = 0; t < T_STEPS - 1; ++t) {
        // critical path: act -> address -> sweep of h_{t+1} = hspec[act]
        const float4* hb = (const float4*)(hspec + (act << 6));
        // h_{t+1}[j] for this lane (for next speculative gates; off critical path)
        float hprev = ha[0];
        #pragma unroll
        for (int a = 1; a < 6; ++a) hprev = (act == a) ? ha[a] : hprev;

        // fused sweep: mlp1 (finishes first) + r/z/n dots — all weights in VGPRs
        f2 p1a = {0.f, 0.f}, p1b = {0.f, 0.f};
        f2 pr = {0.f, 0.f}, pz = {0.f, 0.f}, pn = {0.f, 0.f};
        #pragma unroll
        for (int i = 0; i < 16; ++i) {
            const float4 hv = hb[i];
            const f2 haa = (f2){hv.x, hv.y};
            const f2 hcc = (f2){hv.z, hv.w};
            p1a += haa * w1[2*i]; p1b += hcc * w1[2*i+1];
            pr += haa * wr[2*i]; pr += hcc * wr[2*i+1];
            pz += haa * wz[2*i]; pz += hcc * wz[2*i+1];
            pn += haa * wn[2*i]; pn += hcc * wn[2*i+1];
        }
        const f2 p1 = p1a + p1b;
        const float hid = fast_tanh(p1.x + p1.y + b1j);
        const float hr = pr.x + pr.y;
        const float hz = pz.x + pz.y;
        const float hn = pn.x + pn.y + bhn;

        // mlp2 via DPP wave reduction (critical path: hid -> l -> argmax)
        const float l0 = wave_reduce_add(hid * m2c[0]) + b2[0];
        const float l1 = wave_reduce_add(hid * m2c[1]) + b2[1];
        const float l2 = wave_reduce_add(hid * m2c[2]) + b2[2];
        const float l3 = wave_reduce_add(hid * m2c[3]) + b2[3];
        const float l4 = wave_reduce_add(hid * m2c[4]) + b2[4];
        const float l5 = wave_reduce_add(hid * m2c[5]) + b2[5];

        // speculative gates for ALL 6 actions (independent of argmax; fills
        // the DPP latency window). Produces candidate h_{t+2} values.
        #pragma unroll
        for (int a = 0; a < 6; ++a) {
            const float r = fast_sigmoid(arx[a] + hr);
            const float z = fast_sigmoid(azx[a] + hz);
            const float n = fast_tanh(fmaf(r, hn, anx[a]));
            ha[a] = fmaf(z, hprev - n, n);
        }
        __builtin_amdgcn_wave_barrier();
        #pragma unroll
        for (int a = 0; a < 6; ++a) hspec[a * 64 + j] = ha[a];
        __builtin_amdgcn_wave_barrier();

        // argmax, first-max-wins
        float best = l0; int bi = 0;
        if (l1 > best) { best = l1; bi = 1; }
        if (l2 > best) { best = l2; bi = 2; }
        if (l3 > best) { best = l3; bi = 3; }
        if (l4 > best) { best = l4; bi = 4; }
        if (l5 > best) { best = l5; bi = 5; }
        act = bi;

        if (j < A_DIM) {
            const float outv = (j == 0) ? l0 : (j == 1) ? l1 : (j == 2) ? l2
                             : (j == 3) ? l3 : (j == 4) ? l4 : l5;
            lout[t * A_DIM + j] = outv;
        }
    }
}

extern "C" void kernel_launch(void* const* d_in, const int* in_sizes, int n_in,
                              void* d_out, int out_size, void* d_ws, size_t ws_size,
                              hipStream_t stream) {
    const float* s_h     = (const float*)d_in[0];
    const int*   a_h     = (const int*)  d_in[1];
    const float* b_z     = (const float*)d_in[2];
    const float* conv1_w = (const float*)d_in[3];
    const float* conv1_b = (const float*)d_in[4];
    const float* conv2_w = (const float*)d_in[5];
    const float* conv2_b = (const float*)d_in[6];
    const float* fc_w    = (const float*)d_in[7];
    const float* fc_b    = (const float*)d_in[8];
    const float* emb     = (const float*)d_in[9];
    const float* gru_wih = (const float*)d_in[10];
    const float* gru_whh = (const float*)d_in[11];
    const float* gru_bih = (const float*)d_in[12];
    const float* gru_bhh = (const float*)d_in[13];
    const float* mlp1_w  = (const float*)d_in[14];
    const float* mlp1_b  = (const float*)d_in[15];
    const float* mlp2_w  = (const float*)d_in[16];
    const float* mlp2_b  = (const float*)d_in[17];

    float* out = (float*)d_out;
    float* logits_out = out;                                          // (B,N,127,6)
    float* mask_out   = out + (size_t)BN_TOT * (T_STEPS - 1) * A_DIM; // (B,N,128,1)

    policy_kernel<<<BN_TOT, 64, 0, stream>>>(
        s_h, a_h, b_z, conv1_w, conv1_b, conv2_w, conv2_b, fc_w, fc_b, emb,
        gru_wih, gru_whh, gru_bih, gru_bhh, mlp1_w, mlp1_b, mlp2_w, mlp2_b,
        logits_out, mask_out);
}